// Round 7
// baseline (162.911 us; speedup 1.0000x reference)
//
#include <hip/hip_runtime.h>

#define WTH 64        // nms block = 1 wave
#define NTH 256
#define NBOX 16384
#define NCLSIN 91
#define NCLS 90
#define MAXSEL 100
#define TOPK 200
#define CAP 1024      // global candidate list capacity per (b,c)
#define CANDL 512     // LDS band capacity (C ~ 246 +- 16; >512 = 17 sigma)
#define CBCAP 384     // prefetched boxes/areas
#define BINS 1024     // topk radix bins
#define GRP 4         // BINS / NTH
#define T0 0.985f     // band threshold; exact argmax fallback guards
#define BOXPB 256     // boxes per filter block
#define KSL 16        // per-class LDS slots per filter block
#define OVFC 64       // LDS overflow list capacity
#define CNTSTR 16     // cnt_g stride in ints (64B per counter)

// order-preserving fp32 <-> u32 (strictly monotone for all non-NaN)
__device__ __forceinline__ unsigned fmap(float f) {
    unsigned u = __float_as_uint(f);
    return (u & 0x80000000u) ? ~u : (u | 0x80000000u);
}
__device__ __forceinline__ float funmap(unsigned u) {
    unsigned b = (u & 0x80000000u) ? (u ^ 0x80000000u) : ~u;
    return __uint_as_float(b);
}
__device__ __forceinline__ unsigned long long shfl_xor_u64(unsigned long long v, int mask) {
    unsigned lo = (unsigned)(v & 0xFFFFFFFFull);
    unsigned hi = (unsigned)(v >> 32);
    lo = __shfl_xor(lo, mask, 64);
    hi = __shfl_xor(hi, mask, 64);
    return ((unsigned long long)hi << 32) | (unsigned long long)lo;
}

// exact reference IoU>0.5 test (same op order, real IEEE div, no FMA)
__device__ __forceinline__ bool sup_test(float4 s, float sa, float4 c, float ca) {
    float y1 = fmaxf(s.x, c.x);
    float x1 = fmaxf(s.y, c.y);
    float y2 = fminf(s.z, c.z);
    float x2 = fminf(s.w, c.w);
    float dy = fmaxf(__fsub_rn(y2, y1), 0.f);
    float dx = fmaxf(__fsub_rn(x2, x1), 0.f);
    float inter = __fmul_rn(dy, dx);
    float uni = __fsub_rn(__fadd_rn(sa, ca), inter);
    return (uni > 0.f) && (__fdiv_rn(inter, uni) > 0.5f);
}
__device__ __forceinline__ float box_area(float4 b) {
    return __fmul_rn(__fsub_rn(b.z, b.x), __fsub_rn(b.w, b.y));
}

// ---------------------------------------------------------------------------
// filter_k helper: route one hit into per-class LDS staging. Exact.
// ---------------------------------------------------------------------------
__device__ __forceinline__ void emit_hit(unsigned long long pk, int b, int n0,
                                         int* cnt_s, unsigned long long* ent,
                                         unsigned* ovf_meta,
                                         unsigned long long* ovf_key,
                                         int* sh_ovf, int* cnt_g) {
    unsigned ee = (unsigned)pk;
    int row = (int)ee / NCLSIN;
    int c = (int)ee - row * NCLSIN;
    if (c == 0) return;  // background
    unsigned i = (unsigned)(n0 + row);
    unsigned long long key = (pk & 0xFFFFFFFF00000000ull) | (0xFFFFFFFFu - i);
    int r = atomicAdd(&cnt_s[c], 1);
    if (r < KSL) {
        ent[c * KSL + r] = key;
    } else {
        int o = atomicAdd(sh_ovf, 1);
        if (o < OVFC) {
            ovf_meta[o] = ((unsigned)c << 16) | (unsigned)r;
            ovf_key[o] = key;
        } else {
            // astronomically rare: force exact full fallback for this class
            atomicAdd(&cnt_g[(b * NCLS + c - 1) * CNTSTR], CAP + 1);
        }
    }
}

// ---------------------------------------------------------------------------
// Kernel 0: stream scores once (2x float4/lane). Hits buffered in 4 per-lane
// registers, drained at end; >=5th hit spills to immediate path. One global
// atomicAdd per class per block.
// ---------------------------------------------------------------------------
__global__ __launch_bounds__(NTH) void filter_k(const float* __restrict__ in,
                                                unsigned long long* __restrict__ cand_g,
                                                int* __restrict__ cnt_g) {
    __shared__ int cnt_s[NCLSIN];
    __shared__ int base_s[NCLSIN];
    __shared__ unsigned long long ent[NCLSIN * KSL];
    __shared__ unsigned ovf_meta[OVFC];
    __shared__ unsigned long long ovf_key[OVFC];
    __shared__ int sh_ovf;

    const int tid = threadIdx.x;
    const int n0 = blockIdx.x * BOXPB;
    const int b = blockIdx.y;
    const int NF4 = BOXPB * NCLSIN / 4;

    for (int i = tid; i < NCLSIN; i += NTH) cnt_s[i] = 0;
    if (tid == 0) sh_ovf = 0;
    __syncthreads();

    unsigned long long q0 = 0, q1 = 0, q2 = 0, q3 = 0;
    int lc = 0;

    const float4* src = (const float4*)(in + ((size_t)b * NBOX + n0) * NCLSIN);
    for (int i = tid; i < NF4; i += 2 * NTH) {
        float4 v1 = src[i];
        int i2 = i + NTH;
        bool has2 = i2 < NF4;
        float4 v2 = make_float4(0.f, 0.f, 0.f, 0.f);
        if (has2) v2 = src[i2];
        float mx1 = fmaxf(fmaxf(v1.x, v1.y), fmaxf(v1.z, v1.w));
        float mx2 = fmaxf(fmaxf(v2.x, v2.y), fmaxf(v2.z, v2.w));
        if (fmaxf(mx1, mx2) > T0) {
#pragma unroll
            for (int h = 0; h < 2; ++h) {
                float4 v = h ? v2 : v1;
                float mx = h ? mx2 : mx1;
                int eb = (h ? i2 : i) * 4;
                if (mx > T0) {
                    const float sv[4] = {v.x, v.y, v.z, v.w};
#pragma unroll
                    for (int qq = 0; qq < 4; ++qq) {
                        float s = sv[qq];
                        if (s > T0) {
                            unsigned long long pk =
                                ((unsigned long long)fmap(s) << 32) |
                                (unsigned)(eb + qq);
                            if (lc == 0) q0 = pk;
                            else if (lc == 1) q1 = pk;
                            else if (lc == 2) q2 = pk;
                            else if (lc == 3) q3 = pk;
                            else emit_hit(pk, b, n0, cnt_s, ent, ovf_meta,
                                          ovf_key, &sh_ovf, cnt_g);
                            ++lc;
                        }
                    }
                }
            }
        }
    }
    if (lc > 0) emit_hit(q0, b, n0, cnt_s, ent, ovf_meta, ovf_key, &sh_ovf, cnt_g);
    if (lc > 1) emit_hit(q1, b, n0, cnt_s, ent, ovf_meta, ovf_key, &sh_ovf, cnt_g);
    if (lc > 2) emit_hit(q2, b, n0, cnt_s, ent, ovf_meta, ovf_key, &sh_ovf, cnt_g);
    if (lc > 3) emit_hit(q3, b, n0, cnt_s, ent, ovf_meta, ovf_key, &sh_ovf, cnt_g);
    __syncthreads();

    if (tid >= 1 && tid < NCLSIN) {
        int c = tid;
        int n = cnt_s[c];
        int base = 0;
        if (n > 0) {
            int bc = b * NCLS + c - 1;
            base = atomicAdd(&cnt_g[bc * CNTSTR], n);
            int lim = n < KSL ? n : KSL;
            for (int j = 0; j < lim; ++j) {
                int pos = base + j;
                if (pos < CAP) cand_g[(size_t)bc * CAP + pos] = ent[c * KSL + j];
            }
        }
        base_s[c] = base;
    }
    __syncthreads();

    int no = sh_ovf < OVFC ? sh_ovf : OVFC;
    for (int o = tid; o < no; o += NTH) {
        unsigned m = ovf_meta[o];
        int c = (int)(m >> 16);
        int r = (int)(m & 0xFFFFu);
        int bc = b * NCLS + c - 1;
        int pos = base_s[c] + r;
        if (pos < CAP) cand_g[(size_t)bc * CAP + pos] = ovf_key[o];
    }
}

// single-wave bitonic sort descending, zero-padded to pow2 (cheap barriers)
__device__ __forceinline__ void sort_desc_w(unsigned long long* cand, int M, int tid) {
    int P = 1;
    while (P < M) P <<= 1;
    for (int i = M + tid; i < P; i += WTH) cand[i] = 0ull;
    __syncthreads();
    for (int kk = 2; kk <= P; kk <<= 1) {
        for (int jj = kk >> 1; jj > 0; jj >>= 1) {
            for (int i = tid; i < P; i += WTH) {
                int ixj = i ^ jj;
                if (ixj > i) {
                    unsigned long long a = cand[i], c = cand[ixj];
                    bool sw = ((i & kk) == 0) ? (a < c) : (a > c);
                    if (sw) { cand[i] = c; cand[ixj] = a; }
                }
            }
            __syncthreads();
        }
    }
}

// 256-thread bitonic (topk_k)
__device__ __forceinline__ void sort_desc(unsigned long long* cand, int M, int tid) {
    int P = 1;
    while (P < M) P <<= 1;
    for (int i = M + tid; i < P; i += NTH) cand[i] = 0ull;
    __syncthreads();
    for (int kk = 2; kk <= P; kk <<= 1) {
        for (int jj = kk >> 1; jj > 0; jj >>= 1) {
            for (int i = tid; i < P; i += NTH) {
                int ixj = i ^ jj;
                if (ixj > i) {
                    unsigned long long a = cand[i], c = cand[ixj];
                    bool sw = ((i & kk) == 0) ? (a < c) : (a > c);
                    if (sw) { cand[i] = c; cand[ixj] = a; }
                }
            }
            __syncthreads();
        }
    }
}

__device__ __forceinline__ void bin_select(unsigned* hist, unsigned* gbuf,
                                           int* sh_g, int* sh_b, unsigned* sh_pb,
                                           int tid, unsigned need) {
    unsigned gs = 0;
#pragma unroll
    for (int q = 0; q < GRP; ++q) gs += hist[tid * GRP + q];
    gbuf[tid] = gs;
    __syncthreads();
    for (int off = 1; off < NTH; off <<= 1) {
        unsigned add = (tid >= off) ? gbuf[tid - off] : 0u;
        __syncthreads();
        gbuf[tid] += add;
        __syncthreads();
    }
    if (tid == 0) *sh_g = NTH - 1;
    __syncthreads();
    if (gbuf[tid] >= need && (tid == 0 || gbuf[tid - 1] < need)) *sh_g = tid;
    __syncthreads();
    if (tid == 0) {
        int g = *sh_g;
        unsigned acc = (g > 0) ? gbuf[g - 1] : 0u;
        int bs = g * GRP + (GRP - 1);
        unsigned pb = acc;
#pragma unroll
        for (int q = 0; q < GRP; ++q) {
            acc += hist[g * GRP + q];
            if (acc >= need) { bs = g * GRP + q; pb = acc; break; }
            pb = acc;
        }
        *sh_b = bs; *sh_pb = pb;
    }
    __syncthreads();
}

// ---------------------------------------------------------------------------
// Kernel 1: ONE WAVE per (batch, class). Load band -> 1-wave sort ->
// 2-wide speculative greedy walk (selections in registers, 2 slots/lane).
// Exact argmax fallback (iterative, reference semantics) for all rare paths.
// ---------------------------------------------------------------------------
__global__ __launch_bounds__(WTH, 2) void nms_k(
    const unsigned long long* __restrict__ cand_g,
    const int* __restrict__ cnt_g,
    const float* __restrict__ scores_raw,
    const float4* __restrict__ boxes,
    float* __restrict__ ws_sc, float* __restrict__ ws_bx, int use_band) {
    __shared__ unsigned long long cand[CANDL];  // 4 KB
    __shared__ float4 candbox[CBCAP];           // 6 KB
    __shared__ float carea[CBCAP];              // 1.5 KB

    const int tid = threadIdx.x;  // 0..63, one wave
    const int c0 = blockIdx.x;
    const int b = blockIdx.y;
    const int bc = b * NCLS + c0;
    const float* sraw = scores_raw + (size_t)b * NBOX * NCLSIN + (c0 + 1);
    const float4* bbase = boxes + (size_t)b * NBOX;

    float4 sel0 = make_float4(0.f, 0.f, 0.f, 0.f);
    float4 sel1 = make_float4(0.f, 0.f, 0.f, 0.f);
    float sa0 = 0.f, sa1 = 0.f, ss0 = 0.f, ss1 = 0.f;
    int nsel = 0;
    unsigned long long lastk = ~0ull;

    const int C = use_band ? cnt_g[bc * CNTSTR] : 0;
    if (use_band && C > 0 && C <= CANDL) {
        for (int i = tid; i < C; i += WTH)
            cand[i] = cand_g[(size_t)bc * CAP + i];
        sort_desc_w(cand, C, tid);
        const int W = C < CBCAP ? C : CBCAP;
        for (int i = tid; i < W; i += WTH) {
            float4 bx = bbase[(int)(0xFFFFFFFFu - (unsigned)cand[i])];
            candbox[i] = bx;
            carea[i] = box_area(bx);
        }
        __syncthreads();

        // ---- 2-wide speculative walk over [0, W) ----
        int m = 0;
        unsigned long long ku = cand[0], kv = (W > 1) ? cand[1] : 0ull;
        float4 bu = candbox[0], bv = (W > 1) ? candbox[1] : candbox[0];
        float au = carea[0], av = (W > 1) ? carea[1] : 0.f;
        while (m + 1 < W && nsel < MAXSEL) {
            int i1 = m + 2 < W ? m + 2 : W - 1;     // prefetch next pair
            int i2 = m + 3 < W ? m + 3 : W - 1;
            unsigned long long ku_n = cand[i1], kv_n = cand[i2];
            float4 bu_n = candbox[i1], bv_n = candbox[i2];
            float au_n = carea[i1], av_n = carea[i2];

            bool tU = false, tV = false;
            if (tid < nsel) {
                tU = sup_test(sel0, sa0, bu, au);
                tV = sup_test(sel0, sa0, bv, av);
            }
            if (tid + 64 < nsel) {
                tU = tU || sup_test(sel1, sa1, bu, au);
                tV = tV || sup_test(sel1, sa1, bv, av);
            }
            bool tUV = sup_test(bu, au, bv, av);  // uniform across lanes
            bool anyU = __any(tU);
            bool anyV = __any(tV);
            if (!anyU) {
                if (tid == nsel) { sel0 = bu; sa0 = au; ss0 = funmap((unsigned)(ku >> 32)); }
                if (tid == nsel - 64) { sel1 = bu; sa1 = au; ss1 = funmap((unsigned)(ku >> 32)); }
                nsel++;
                if (nsel < MAXSEL && !anyV && !tUV) {
                    if (tid == nsel) { sel0 = bv; sa0 = av; ss0 = funmap((unsigned)(kv >> 32)); }
                    if (tid == nsel - 64) { sel1 = bv; sa1 = av; ss1 = funmap((unsigned)(kv >> 32)); }
                    nsel++;
                }
            } else if (!anyV) {
                if (tid == nsel) { sel0 = bv; sa0 = av; ss0 = funmap((unsigned)(kv >> 32)); }
                if (tid == nsel - 64) { sel1 = bv; sa1 = av; ss1 = funmap((unsigned)(kv >> 32)); }
                nsel++;
            }
            ku = ku_n; kv = kv_n; bu = bu_n; bv = bv_n; au = au_n; av = av_n;
            m += 2;
        }
        // odd tail within [0, W)
        if (m < W && nsel < MAXSEL) {
            unsigned long long k = cand[m];
            float4 bx = candbox[m];
            float ca = carea[m];
            bool sup = false;
            if (tid < nsel) sup = sup_test(sel0, sa0, bx, ca);
            if (tid + 64 < nsel) sup = sup || sup_test(sel1, sa1, bx, ca);
            if (!__any(sup)) {
                if (tid == nsel) { sel0 = bx; sa0 = ca; ss0 = funmap((unsigned)(k >> 32)); }
                if (tid == nsel - 64) { sel1 = bx; sa1 = ca; ss1 = funmap((unsigned)(k >> 32)); }
                nsel++;
            }
        }
        // slow tail [W, C): global box fetch (uniform -> broadcast)
        for (int mm = W; mm < C && nsel < MAXSEL; ++mm) {
            unsigned long long k = cand[mm];
            float4 bx = bbase[(int)(0xFFFFFFFFu - (unsigned)k)];
            float ca = box_area(bx);
            bool sup = false;
            if (tid < nsel) sup = sup_test(sel0, sa0, bx, ca);
            if (tid + 64 < nsel) sup = sup || sup_test(sel1, sa1, bx, ca);
            if (!__any(sup)) {
                if (tid == nsel) { sel0 = bx; sa0 = ca; ss0 = funmap((unsigned)(k >> 32)); }
                if (tid == nsel - 64) { sel1 = bx; sa1 = ca; ss1 = funmap((unsigned)(k >> 32)); }
                nsel++;
            }
        }
        lastk = cand[C - 1];  // smallest band key (all non-band keys are below)
    }

    // ---- exact iterative-argmax fallback (reference semantics; never runs
    // on this distribution, guards C==0 / C>CANDL / band-exhausted cases) ----
    while (nsel < MAXSEL) {
        unsigned long long best = 0ull;
        for (int i = tid; i < NBOX; i += WTH) {
            float s = sraw[(size_t)i * NCLSIN];
            if (s > 0.3f) {
                unsigned long long key =
                    ((unsigned long long)fmap(s) << 32) | (0xFFFFFFFFu - (unsigned)i);
                if (key < lastk && key > best) best = key;
            }
        }
#pragma unroll
        for (int off = 32; off > 0; off >>= 1) {
            unsigned long long o = shfl_xor_u64(best, off);
            best = best > o ? best : o;
        }
        if (best == 0ull) break;  // no eligible box left
        lastk = best;
        float4 bx = bbase[(int)(0xFFFFFFFFu - (unsigned)best)];
        float ca = box_area(bx);
        bool sup = false;
        if (tid < nsel) sup = sup_test(sel0, sa0, bx, ca);
        if (tid + 64 < nsel) sup = sup || sup_test(sel1, sa1, bx, ca);
        if (!__any(sup)) {  // if suppressed, it was masked in reference: skip
            if (tid == nsel) { sel0 = bx; sa0 = ca; ss0 = funmap((unsigned)(best >> 32)); }
            if (tid == nsel - 64) { sel1 = bx; sa1 = ca; ss1 = funmap((unsigned)(best >> 32)); }
            nsel++;
        }
    }

    // ---- outputs: selections in greedy order, zero-padded ----
    {
        float* scp = ws_sc + (size_t)bc * MAXSEL;
        float4* bxp = (float4*)(ws_bx + (size_t)bc * MAXSEL * 4);
        bool v = tid < nsel;
        scp[tid] = v ? ss0 : 0.f;
        bxp[tid] = v ? sel0 : make_float4(0.f, 0.f, 0.f, 0.f);
        int j1 = tid + 64;
        if (j1 < MAXSEL) {
            bool v2 = j1 < nsel;
            scp[j1] = v2 ? ss1 : 0.f;
            bxp[j1] = v2 ? sel1 : make_float4(0.f, 0.f, 0.f, 0.f);
        }
    }
}

// ---------------------------------------------------------------------------
// Kernel 2: one block per batch: stable top-200 of 9000 via radix-select+sort.
// ---------------------------------------------------------------------------
__global__ __launch_bounds__(NTH) void topk_k(const float* __restrict__ ws_sc,
                                              const float* __restrict__ ws_bx,
                                              float* __restrict__ out_sc,
                                              float* __restrict__ out_bx) {
    __shared__ unsigned hist[BINS];
    __shared__ unsigned gbuf[NTH];
    __shared__ unsigned long long cand[CAP];
    __shared__ unsigned sh_kmax, sh_pb;
    __shared__ int sh_E, sh_g, sh_b, sh_cnt;

    const int tid = threadIdx.x;
    const int b = blockIdx.x;
    const int NF = NCLS * MAXSEL;  // 9000
    const float* sp = ws_sc + (size_t)b * NF;

    unsigned km = 0, ce = 0;
    for (int f = tid; f < NF; f += NTH) {
        unsigned k = __float_as_uint(sp[f]);
        if (k) { ce++; km = km > k ? km : k; }
    }
#pragma unroll
    for (int off = 32; off > 0; off >>= 1) {
        unsigned o = (unsigned)__shfl_xor((int)km, off, 64);
        km = km > o ? km : o;
        ce += (unsigned)__shfl_xor((int)ce, off, 64);
    }
    if ((tid & 63) == 0) { gbuf[tid >> 6] = km; gbuf[8 + (tid >> 6)] = ce; }
    __syncthreads();
    if (tid == 0) {
        unsigned m2 = 0, c2 = 0;
        for (int w = 0; w < NTH / 64; ++w) {
            m2 = m2 > gbuf[w] ? m2 : gbuf[w];
            c2 += gbuf[8 + w];
        }
        sh_kmax = m2; sh_E = (int)c2;
    }
    __syncthreads();
    const int E = sh_E;
    const unsigned kmax = sh_kmax;

    unsigned thr = 1u;
    if (E > TOPK) {
        for (int shift = 8;; shift += 4) {
            for (int i = tid; i < BINS; i += NTH) hist[i] = 0u;
            __syncthreads();
            for (int f = tid; f < NF; f += NTH) {
                unsigned k = __float_as_uint(sp[f]);
                if (k) {
                    unsigned bin = (kmax - k) >> shift;
                    if (bin < BINS - 1) atomicAdd(&hist[bin], 1u);
                }
            }
            __syncthreads();
            bin_select(hist, gbuf, &sh_g, &sh_b, &sh_pb, tid, (unsigned)TOPK);
            if (sh_b < BINS - 1) {
                long long t = (long long)kmax - ((long long)(sh_b + 1) << shift) + 1;
                thr = (t < 1) ? 1u : (unsigned)t;
                break;
            }
        }
    }

    if (tid == 0) sh_cnt = 0;
    __syncthreads();
    for (int f = tid; f < NF; f += NTH) {
        unsigned k = __float_as_uint(sp[f]);
        if (k >= thr) {
            int pos = atomicAdd(&sh_cnt, 1);
            if (pos < CAP)
                cand[pos] = ((unsigned long long)k << 32) | (0xFFFFFFFFu - (unsigned)f);
        }
    }
    __syncthreads();
    int M = sh_cnt < CAP ? sh_cnt : CAP;

    if (M < TOPK) {
        int lim = M + TOPK;
        if (lim > NF) lim = NF;
        for (int f = tid; f < lim; f += NTH) {
            unsigned k = __float_as_uint(sp[f]);
            if (k == 0) {
                int pos = atomicAdd(&sh_cnt, 1);
                if (pos < CAP)
                    cand[pos] = (unsigned long long)(0xFFFFFFFFu - (unsigned)f);
            }
        }
        __syncthreads();
        M = sh_cnt < CAP ? sh_cnt : CAP;
    }

    sort_desc(cand, M, tid);

    for (int k = tid; k < TOPK; k += NTH) {
        float cls = 0.f, s = 0.f;
        float4 bx = make_float4(0.f, 0.f, 0.f, 0.f);
        if (k < M) {
            unsigned long long key = cand[k];
            unsigned f = 0xFFFFFFFFu - (unsigned)key;
            s = __uint_as_float((unsigned)(key >> 32));
            cls = (s > 0.f) ? (float)(f / MAXSEL + 1) : 0.f;
            bx = *(const float4*)(ws_bx + ((size_t)b * NF + f) * 4);
        }
        out_sc[((size_t)b * TOPK + k) * 2 + 0] = cls;
        out_sc[((size_t)b * TOPK + k) * 2 + 1] = s;
        ((float4*)out_bx)[(size_t)b * TOPK + k] = bx;
    }
}

// ---------------------------------------------------------------------------
extern "C" void kernel_launch(void* const* d_in, const int* in_sizes, int n_in,
                              void* d_out, int out_size, void* d_ws, size_t ws_size,
                              hipStream_t stream) {
    const float* scores = (const float*)d_in[0];
    const float4* boxes = (const float4*)d_in[1];
    float* out = (float*)d_out;

    const int B = in_sizes[1] / (NBOX * 4);
    const int NBC = B * NCLS;

    // ws layout: cnt [NBC * CNTSTR ints] | cand [NBC*CAP u64] | sc | bx
    size_t off_cand = ((size_t)NBC * CNTSTR * 4 + 15) & ~(size_t)15;
    size_t off_sc = off_cand + (size_t)NBC * CAP * 8;
    size_t off_bx = off_sc + (size_t)NBC * MAXSEL * 4;
    size_t need = off_bx + (size_t)NBC * MAXSEL * 16;

    char* ws = (char*)d_ws;
    bool use_band = ws_size >= need;

    int* cnt_g;
    unsigned long long* cand_g;
    float *ws_sc, *ws_bx;
    if (use_band) {
        cnt_g = (int*)ws;
        cand_g = (unsigned long long*)(ws + off_cand);
        ws_sc = (float*)(ws + off_sc);
        ws_bx = (float*)(ws + off_bx);
    } else {
        cnt_g = (int*)ws;                  // unused
        cand_g = (unsigned long long*)ws;  // unused
        ws_sc = (float*)ws;
        ws_bx = ws_sc + (size_t)NBC * MAXSEL;
    }

    if (use_band) {
        hipMemsetAsync(cnt_g, 0, (size_t)NBC * CNTSTR * 4, stream);
        filter_k<<<dim3(NBOX / BOXPB, B), NTH, 0, stream>>>(scores, cand_g, cnt_g);
    }
    nms_k<<<dim3(NCLS, B), WTH, 0, stream>>>(cand_g, cnt_g, scores, boxes,
                                             ws_sc, ws_bx, use_band ? 1 : 0);
    topk_k<<<B, NTH, 0, stream>>>(ws_sc, ws_bx, out, out + (size_t)B * TOPK * 2);
}

// Round 8
// 138.395 us; speedup vs baseline: 1.1771x; 1.1771x over previous
//
#include <hip/hip_runtime.h>

#define WTH 64        // walk block = 1 wave
#define NTH 256
#define NBOX 16384
#define NCLSIN 91
#define NCLS 90
#define MAXSEL 100
#define TOPK 200
#define CAP 1024      // global candidate list stride per (b,c)
#define CANDL 512     // band capacity handled by prep/walk (C ~ 246 +- 16)
#define CBCAP 384     // staged boxes/areas
#define BINS 1024     // topk radix bins
#define GRP 4         // BINS / NTH
#define T0 0.985f     // band threshold; exact argmax fallback guards
#define BOXPB 256     // boxes per filter block
#define KSL 16        // per-class LDS slots per filter block
#define OVFC 64       // LDS overflow list capacity
#define CNTSTR 16     // cnt_g stride in ints (64B per counter)

// order-preserving fp32 <-> u32 (strictly monotone for all non-NaN)
__device__ __forceinline__ unsigned fmap(float f) {
    unsigned u = __float_as_uint(f);
    return (u & 0x80000000u) ? ~u : (u | 0x80000000u);
}
__device__ __forceinline__ float funmap(unsigned u) {
    unsigned b = (u & 0x80000000u) ? (u ^ 0x80000000u) : ~u;
    return __uint_as_float(b);
}
__device__ __forceinline__ unsigned long long shfl_xor_u64(unsigned long long v, int mask) {
    unsigned lo = (unsigned)(v & 0xFFFFFFFFull);
    unsigned hi = (unsigned)(v >> 32);
    lo = __shfl_xor(lo, mask, 64);
    hi = __shfl_xor(hi, mask, 64);
    return ((unsigned long long)hi << 32) | (unsigned long long)lo;
}

// exact reference IoU>0.5 test (same op order, real IEEE div, no FMA)
__device__ __forceinline__ bool sup_test(float4 s, float sa, float4 c, float ca) {
    float y1 = fmaxf(s.x, c.x);
    float x1 = fmaxf(s.y, c.y);
    float y2 = fminf(s.z, c.z);
    float x2 = fminf(s.w, c.w);
    float dy = fmaxf(__fsub_rn(y2, y1), 0.f);
    float dx = fmaxf(__fsub_rn(x2, x1), 0.f);
    float inter = __fmul_rn(dy, dx);
    float uni = __fsub_rn(__fadd_rn(sa, ca), inter);
    return (uni > 0.f) && (__fdiv_rn(inter, uni) > 0.5f);
}
__device__ __forceinline__ float box_area(float4 b) {
    return __fmul_rn(__fsub_rn(b.z, b.x), __fsub_rn(b.w, b.y));
}

// ---------------------------------------------------------------------------
// filter_k helper: route one hit into per-class LDS staging. Exact.
// ---------------------------------------------------------------------------
__device__ __forceinline__ void emit_hit(unsigned long long pk, int b, int n0,
                                         int* cnt_s, unsigned long long* ent,
                                         unsigned* ovf_meta,
                                         unsigned long long* ovf_key,
                                         int* sh_ovf, int* cnt_g) {
    unsigned ee = (unsigned)pk;
    int row = (int)ee / NCLSIN;
    int c = (int)ee - row * NCLSIN;
    if (c == 0) return;  // background
    unsigned i = (unsigned)(n0 + row);
    unsigned long long key = (pk & 0xFFFFFFFF00000000ull) | (0xFFFFFFFFu - i);
    int r = atomicAdd(&cnt_s[c], 1);
    if (r < KSL) {
        ent[c * KSL + r] = key;
    } else {
        int o = atomicAdd(sh_ovf, 1);
        if (o < OVFC) {
            ovf_meta[o] = ((unsigned)c << 16) | (unsigned)r;
            ovf_key[o] = key;
        } else {
            // astronomically rare: force exact full fallback for this class
            atomicAdd(&cnt_g[(b * NCLS + c - 1) * CNTSTR], CAP + 1);
        }
    }
}

// ---------------------------------------------------------------------------
// Kernel 0: stream scores once (2x float4/lane). Hits buffered in 4 per-lane
// registers, drained at end; >=5th hit spills to immediate path.
// ---------------------------------------------------------------------------
__global__ __launch_bounds__(NTH) void filter_k(const float* __restrict__ in,
                                                unsigned long long* __restrict__ cand_g,
                                                int* __restrict__ cnt_g) {
    __shared__ int cnt_s[NCLSIN];
    __shared__ int base_s[NCLSIN];
    __shared__ unsigned long long ent[NCLSIN * KSL];
    __shared__ unsigned ovf_meta[OVFC];
    __shared__ unsigned long long ovf_key[OVFC];
    __shared__ int sh_ovf;

    const int tid = threadIdx.x;
    const int n0 = blockIdx.x * BOXPB;
    const int b = blockIdx.y;
    const int NF4 = BOXPB * NCLSIN / 4;

    for (int i = tid; i < NCLSIN; i += NTH) cnt_s[i] = 0;
    if (tid == 0) sh_ovf = 0;
    __syncthreads();

    unsigned long long q0 = 0, q1 = 0, q2 = 0, q3 = 0;
    int lc = 0;

    const float4* src = (const float4*)(in + ((size_t)b * NBOX + n0) * NCLSIN);
    for (int i = tid; i < NF4; i += 2 * NTH) {
        float4 v1 = src[i];
        int i2 = i + NTH;
        bool has2 = i2 < NF4;
        float4 v2 = make_float4(0.f, 0.f, 0.f, 0.f);
        if (has2) v2 = src[i2];
        float mx1 = fmaxf(fmaxf(v1.x, v1.y), fmaxf(v1.z, v1.w));
        float mx2 = fmaxf(fmaxf(v2.x, v2.y), fmaxf(v2.z, v2.w));
        if (fmaxf(mx1, mx2) > T0) {
#pragma unroll
            for (int h = 0; h < 2; ++h) {
                float4 v = h ? v2 : v1;
                float mx = h ? mx2 : mx1;
                int eb = (h ? i2 : i) * 4;
                if (mx > T0) {
                    const float sv[4] = {v.x, v.y, v.z, v.w};
#pragma unroll
                    for (int qq = 0; qq < 4; ++qq) {
                        float s = sv[qq];
                        if (s > T0) {
                            unsigned long long pk =
                                ((unsigned long long)fmap(s) << 32) |
                                (unsigned)(eb + qq);
                            if (lc == 0) q0 = pk;
                            else if (lc == 1) q1 = pk;
                            else if (lc == 2) q2 = pk;
                            else if (lc == 3) q3 = pk;
                            else emit_hit(pk, b, n0, cnt_s, ent, ovf_meta,
                                          ovf_key, &sh_ovf, cnt_g);
                            ++lc;
                        }
                    }
                }
            }
        }
    }
    if (lc > 0) emit_hit(q0, b, n0, cnt_s, ent, ovf_meta, ovf_key, &sh_ovf, cnt_g);
    if (lc > 1) emit_hit(q1, b, n0, cnt_s, ent, ovf_meta, ovf_key, &sh_ovf, cnt_g);
    if (lc > 2) emit_hit(q2, b, n0, cnt_s, ent, ovf_meta, ovf_key, &sh_ovf, cnt_g);
    if (lc > 3) emit_hit(q3, b, n0, cnt_s, ent, ovf_meta, ovf_key, &sh_ovf, cnt_g);
    __syncthreads();

    if (tid >= 1 && tid < NCLSIN) {
        int c = tid;
        int n = cnt_s[c];
        int base = 0;
        if (n > 0) {
            int bc = b * NCLS + c - 1;
            base = atomicAdd(&cnt_g[bc * CNTSTR], n);
            int lim = n < KSL ? n : KSL;
            for (int j = 0; j < lim; ++j) {
                int pos = base + j;
                if (pos < CAP) cand_g[(size_t)bc * CAP + pos] = ent[c * KSL + j];
            }
        }
        base_s[c] = base;
    }
    __syncthreads();

    int no = sh_ovf < OVFC ? sh_ovf : OVFC;
    for (int o = tid; o < no; o += NTH) {
        unsigned m = ovf_meta[o];
        int c = (int)(m >> 16);
        int r = (int)(m & 0xFFFFu);
        int bc = b * NCLS + c - 1;
        int pos = base_s[c] + r;
        if (pos < CAP) cand_g[(size_t)bc * CAP + pos] = ovf_key[o];
    }
}

// ---------------------------------------------------------------------------
// Kernel 1a: prep — sort each band list descending, in place. 256 threads,
// 4 KB LDS, pure parallel work (attribution: "sort cost" shows up here).
// ---------------------------------------------------------------------------
__global__ __launch_bounds__(NTH) void prep_k(unsigned long long* __restrict__ cand_g,
                                              const int* __restrict__ cnt_g) {
    __shared__ unsigned long long s[CANDL];  // 4 KB
    const int tid = threadIdx.x;
    const int bc = blockIdx.y * NCLS + blockIdx.x;
    const int C = cnt_g[bc * CNTSTR];
    if (C <= 0 || C > CANDL) return;  // uniform; walk_k handles via fallback

    unsigned long long* cg = cand_g + (size_t)bc * CAP;
    for (int i = tid; i < C; i += NTH) s[i] = cg[i];
    int P = 1;
    while (P < C) P <<= 1;
    for (int i = C + tid; i < P; i += NTH) s[i] = 0ull;
    __syncthreads();
    for (int kk = 2; kk <= P; kk <<= 1) {
        for (int jj = kk >> 1; jj > 0; jj >>= 1) {
            for (int i = tid; i < P; i += NTH) {
                int ixj = i ^ jj;
                if (ixj > i) {
                    unsigned long long a = s[i], c = s[ixj];
                    bool sw = ((i & kk) == 0) ? (a < c) : (a > c);
                    if (sw) { s[i] = c; s[ixj] = a; }
                }
            }
            __syncthreads();
        }
    }
    for (int i = tid; i < C; i += NTH) cg[i] = s[i];
}

// ---------------------------------------------------------------------------
// Kernel 1b: walk — ONE WAVE per (batch, class). Stage sorted band into LDS
// (keys + boxes + areas), prefetched serial greedy walk, selections in
// 2 register slots/lane. Exact argmax fallback for all rare paths.
// ---------------------------------------------------------------------------
__global__ __launch_bounds__(WTH) void walk_k(
    const unsigned long long* __restrict__ cand_g,
    const int* __restrict__ cnt_g,
    const float* __restrict__ scores_raw,
    const float4* __restrict__ boxes,
    float* __restrict__ ws_sc, float* __restrict__ ws_bx, int use_band) {
    __shared__ unsigned long long kk[CANDL];  // 4 KB
    __shared__ float4 kbox[CBCAP];            // 6 KB
    __shared__ float karea[CBCAP];            // 1.5 KB

    const int tid = threadIdx.x;  // 0..63
    const int bc = blockIdx.x;
    const int b = bc / NCLS;
    const int c0 = bc - b * NCLS;
    const float* sraw = scores_raw + (size_t)b * NBOX * NCLSIN + (c0 + 1);
    const float4* bbase = boxes + (size_t)b * NBOX;

    float4 sel0 = make_float4(0.f, 0.f, 0.f, 0.f);
    float4 sel1 = make_float4(0.f, 0.f, 0.f, 0.f);
    float sa0 = 0.f, sa1 = 0.f, ss0 = 0.f, ss1 = 0.f;
    int nsel = 0;
    unsigned long long lastk = ~0ull;

    const int C = use_band ? cnt_g[bc * CNTSTR] : 0;
    if (use_band && C > 0 && C <= CANDL) {
        for (int i = tid; i < C; i += WTH)
            kk[i] = cand_g[(size_t)bc * CAP + i];
        __syncthreads();
        const int W = C < CBCAP ? C : CBCAP;
        for (int i = tid; i < W; i += WTH) {
            float4 bx = bbase[(int)(0xFFFFFFFFu - (unsigned)kk[i])];
            kbox[i] = bx;
            karea[i] = box_area(bx);
        }
        __syncthreads();

        // prefetched serial walk over [0, W)
        unsigned long long kcur = kk[0];
        float4 bcur = kbox[0];
        float acur = karea[0];
        for (int m = 0; m < W && nsel < MAXSEL; ++m) {
            int mn = (m + 1 < W) ? m + 1 : m;
            unsigned long long knxt = kk[mn];   // prefetch next (hides LDS lat)
            float4 bnxt = kbox[mn];
            float anxt = karea[mn];
            bool sup = false;
            if (tid < nsel) sup = sup_test(sel0, sa0, bcur, acur);
            if (tid + 64 < nsel) sup = sup || sup_test(sel1, sa1, bcur, acur);
            if (!__any(sup)) {
                if (tid == nsel) { sel0 = bcur; sa0 = acur; ss0 = funmap((unsigned)(kcur >> 32)); }
                if (tid == nsel - 64) { sel1 = bcur; sa1 = acur; ss1 = funmap((unsigned)(kcur >> 32)); }
                nsel++;
            }
            kcur = knxt; bcur = bnxt; acur = anxt;
        }
        // slow tail [W, C): global box fetch (uniform -> broadcast)
        for (int mm = W; mm < C && nsel < MAXSEL; ++mm) {
            unsigned long long k = kk[mm];
            float4 bx = bbase[(int)(0xFFFFFFFFu - (unsigned)k)];
            float ca = box_area(bx);
            bool sup = false;
            if (tid < nsel) sup = sup_test(sel0, sa0, bx, ca);
            if (tid + 64 < nsel) sup = sup || sup_test(sel1, sa1, bx, ca);
            if (!__any(sup)) {
                if (tid == nsel) { sel0 = bx; sa0 = ca; ss0 = funmap((unsigned)(k >> 32)); }
                if (tid == nsel - 64) { sel1 = bx; sa1 = ca; ss1 = funmap((unsigned)(k >> 32)); }
                nsel++;
            }
        }
        lastk = kk[C - 1];  // smallest band key (all non-band keys are below)
    }

    // ---- exact iterative-argmax fallback (reference semantics; guards
    // C==0 / C>CANDL / band-exhausted; never runs on this distribution) ----
    while (nsel < MAXSEL) {
        unsigned long long best = 0ull;
        for (int i = tid; i < NBOX; i += WTH) {
            float s = sraw[(size_t)i * NCLSIN];
            if (s > 0.3f) {
                unsigned long long key =
                    ((unsigned long long)fmap(s) << 32) | (0xFFFFFFFFu - (unsigned)i);
                if (key < lastk && key > best) best = key;
            }
        }
#pragma unroll
        for (int off = 32; off > 0; off >>= 1) {
            unsigned long long o = shfl_xor_u64(best, off);
            best = best > o ? best : o;
        }
        if (best == 0ull) break;  // no eligible box left
        lastk = best;
        float4 bx = bbase[(int)(0xFFFFFFFFu - (unsigned)best)];
        float ca = box_area(bx);
        bool sup = false;
        if (tid < nsel) sup = sup_test(sel0, sa0, bx, ca);
        if (tid + 64 < nsel) sup = sup || sup_test(sel1, sa1, bx, ca);
        if (!__any(sup)) {  // if suppressed, it was masked in reference: skip
            if (tid == nsel) { sel0 = bx; sa0 = ca; ss0 = funmap((unsigned)(best >> 32)); }
            if (tid == nsel - 64) { sel1 = bx; sa1 = ca; ss1 = funmap((unsigned)(best >> 32)); }
            nsel++;
        }
    }

    // ---- outputs: selections in greedy order, zero-padded ----
    {
        float* scp = ws_sc + (size_t)bc * MAXSEL;
        float4* bxp = (float4*)(ws_bx + (size_t)bc * MAXSEL * 4);
        bool v = tid < nsel;
        scp[tid] = v ? ss0 : 0.f;
        bxp[tid] = v ? sel0 : make_float4(0.f, 0.f, 0.f, 0.f);
        int j1 = tid + 64;
        if (j1 < MAXSEL) {
            bool v2 = j1 < nsel;
            scp[j1] = v2 ? ss1 : 0.f;
            bxp[j1] = v2 ? sel1 : make_float4(0.f, 0.f, 0.f, 0.f);
        }
    }
}

__device__ __forceinline__ void bin_select(unsigned* hist, unsigned* gbuf,
                                           int* sh_g, int* sh_b, unsigned* sh_pb,
                                           int tid, unsigned need) {
    unsigned gs = 0;
#pragma unroll
    for (int q = 0; q < GRP; ++q) gs += hist[tid * GRP + q];
    gbuf[tid] = gs;
    __syncthreads();
    for (int off = 1; off < NTH; off <<= 1) {
        unsigned add = (tid >= off) ? gbuf[tid - off] : 0u;
        __syncthreads();
        gbuf[tid] += add;
        __syncthreads();
    }
    if (tid == 0) *sh_g = NTH - 1;
    __syncthreads();
    if (gbuf[tid] >= need && (tid == 0 || gbuf[tid - 1] < need)) *sh_g = tid;
    __syncthreads();
    if (tid == 0) {
        int g = *sh_g;
        unsigned acc = (g > 0) ? gbuf[g - 1] : 0u;
        int bs = g * GRP + (GRP - 1);
        unsigned pb = acc;
#pragma unroll
        for (int q = 0; q < GRP; ++q) {
            acc += hist[g * GRP + q];
            if (acc >= need) { bs = g * GRP + q; pb = acc; break; }
            pb = acc;
        }
        *sh_b = bs; *sh_pb = pb;
    }
    __syncthreads();
}

__device__ __forceinline__ void sort_desc(unsigned long long* cand, int M, int tid) {
    int P = 1;
    while (P < M) P <<= 1;
    for (int i = M + tid; i < P; i += NTH) cand[i] = 0ull;
    __syncthreads();
    for (int kk = 2; kk <= P; kk <<= 1) {
        for (int jj = kk >> 1; jj > 0; jj >>= 1) {
            for (int i = tid; i < P; i += NTH) {
                int ixj = i ^ jj;
                if (ixj > i) {
                    unsigned long long a = cand[i], c = cand[ixj];
                    bool sw = ((i & kk) == 0) ? (a < c) : (a > c);
                    if (sw) { cand[i] = c; cand[ixj] = a; }
                }
            }
            __syncthreads();
        }
    }
}

// ---------------------------------------------------------------------------
// Kernel 2: one block per batch: stable top-200 of 9000 via radix-select+sort.
// ---------------------------------------------------------------------------
__global__ __launch_bounds__(NTH) void topk_k(const float* __restrict__ ws_sc,
                                              const float* __restrict__ ws_bx,
                                              float* __restrict__ out_sc,
                                              float* __restrict__ out_bx) {
    __shared__ unsigned hist[BINS];
    __shared__ unsigned gbuf[NTH];
    __shared__ unsigned long long cand[CAP];
    __shared__ unsigned sh_kmax, sh_pb;
    __shared__ int sh_E, sh_g, sh_b, sh_cnt;

    const int tid = threadIdx.x;
    const int b = blockIdx.x;
    const int NF = NCLS * MAXSEL;  // 9000
    const float* sp = ws_sc + (size_t)b * NF;

    unsigned km = 0, ce = 0;
    for (int f = tid; f < NF; f += NTH) {
        unsigned k = __float_as_uint(sp[f]);
        if (k) { ce++; km = km > k ? km : k; }
    }
#pragma unroll
    for (int off = 32; off > 0; off >>= 1) {
        unsigned o = (unsigned)__shfl_xor((int)km, off, 64);
        km = km > o ? km : o;
        ce += (unsigned)__shfl_xor((int)ce, off, 64);
    }
    if ((tid & 63) == 0) { gbuf[tid >> 6] = km; gbuf[8 + (tid >> 6)] = ce; }
    __syncthreads();
    if (tid == 0) {
        unsigned m2 = 0, c2 = 0;
        for (int w = 0; w < NTH / 64; ++w) {
            m2 = m2 > gbuf[w] ? m2 : gbuf[w];
            c2 += gbuf[8 + w];
        }
        sh_kmax = m2; sh_E = (int)c2;
    }
    __syncthreads();
    const int E = sh_E;
    const unsigned kmax = sh_kmax;

    unsigned thr = 1u;
    if (E > TOPK) {
        for (int shift = 8;; shift += 4) {
            for (int i = tid; i < BINS; i += NTH) hist[i] = 0u;
            __syncthreads();
            for (int f = tid; f < NF; f += NTH) {
                unsigned k = __float_as_uint(sp[f]);
                if (k) {
                    unsigned bin = (kmax - k) >> shift;
                    if (bin < BINS - 1) atomicAdd(&hist[bin], 1u);
                }
            }
            __syncthreads();
            bin_select(hist, gbuf, &sh_g, &sh_b, &sh_pb, tid, (unsigned)TOPK);
            if (sh_b < BINS - 1) {
                long long t = (long long)kmax - ((long long)(sh_b + 1) << shift) + 1;
                thr = (t < 1) ? 1u : (unsigned)t;
                break;
            }
        }
    }

    if (tid == 0) sh_cnt = 0;
    __syncthreads();
    for (int f = tid; f < NF; f += NTH) {
        unsigned k = __float_as_uint(sp[f]);
        if (k >= thr) {
            int pos = atomicAdd(&sh_cnt, 1);
            if (pos < CAP)
                cand[pos] = ((unsigned long long)k << 32) | (0xFFFFFFFFu - (unsigned)f);
        }
    }
    __syncthreads();
    int M = sh_cnt < CAP ? sh_cnt : CAP;

    if (M < TOPK) {
        int lim = M + TOPK;
        if (lim > NF) lim = NF;
        for (int f = tid; f < lim; f += NTH) {
            unsigned k = __float_as_uint(sp[f]);
            if (k == 0) {
                int pos = atomicAdd(&sh_cnt, 1);
                if (pos < CAP)
                    cand[pos] = (unsigned long long)(0xFFFFFFFFu - (unsigned)f);
            }
        }
        __syncthreads();
        M = sh_cnt < CAP ? sh_cnt : CAP;
    }

    sort_desc(cand, M, tid);

    for (int k = tid; k < TOPK; k += NTH) {
        float cls = 0.f, s = 0.f;
        float4 bx = make_float4(0.f, 0.f, 0.f, 0.f);
        if (k < M) {
            unsigned long long key = cand[k];
            unsigned f = 0xFFFFFFFFu - (unsigned)key;
            s = __uint_as_float((unsigned)(key >> 32));
            cls = (s > 0.f) ? (float)(f / MAXSEL + 1) : 0.f;
            bx = *(const float4*)(ws_bx + ((size_t)b * NF + f) * 4);
        }
        out_sc[((size_t)b * TOPK + k) * 2 + 0] = cls;
        out_sc[((size_t)b * TOPK + k) * 2 + 1] = s;
        ((float4*)out_bx)[(size_t)b * TOPK + k] = bx;
    }
}

// ---------------------------------------------------------------------------
extern "C" void kernel_launch(void* const* d_in, const int* in_sizes, int n_in,
                              void* d_out, int out_size, void* d_ws, size_t ws_size,
                              hipStream_t stream) {
    const float* scores = (const float*)d_in[0];
    const float4* boxes = (const float4*)d_in[1];
    float* out = (float*)d_out;

    const int B = in_sizes[1] / (NBOX * 4);
    const int NBC = B * NCLS;

    // ws layout: cnt [NBC * CNTSTR ints] | cand [NBC*CAP u64] | sc | bx
    size_t off_cand = ((size_t)NBC * CNTSTR * 4 + 15) & ~(size_t)15;
    size_t off_sc = off_cand + (size_t)NBC * CAP * 8;
    size_t off_bx = off_sc + (size_t)NBC * MAXSEL * 4;
    size_t need = off_bx + (size_t)NBC * MAXSEL * 16;

    char* ws = (char*)d_ws;
    bool use_band = ws_size >= need;

    int* cnt_g;
    unsigned long long* cand_g;
    float *ws_sc, *ws_bx;
    if (use_band) {
        cnt_g = (int*)ws;
        cand_g = (unsigned long long*)(ws + off_cand);
        ws_sc = (float*)(ws + off_sc);
        ws_bx = (float*)(ws + off_bx);
    } else {
        cnt_g = (int*)ws;                  // unused
        cand_g = (unsigned long long*)ws;  // unused
        ws_sc = (float*)ws;
        ws_bx = ws_sc + (size_t)NBC * MAXSEL;
    }

    if (use_band) {
        hipMemsetAsync(cnt_g, 0, (size_t)NBC * CNTSTR * 4, stream);
        filter_k<<<dim3(NBOX / BOXPB, B), NTH, 0, stream>>>(scores, cand_g, cnt_g);
        prep_k<<<dim3(NCLS, B), NTH, 0, stream>>>(cand_g, cnt_g);
    }
    walk_k<<<NBC, WTH, 0, stream>>>(cand_g, cnt_g, scores, boxes,
                                    ws_sc, ws_bx, use_band ? 1 : 0);
    topk_k<<<B, NTH, 0, stream>>>(ws_sc, ws_bx, out, out + (size_t)B * TOPK * 2);
}

// Round 9
// 137.842 us; speedup vs baseline: 1.1819x; 1.0040x over previous
//
#include <hip/hip_runtime.h>

#define WTH 64        // walk block = 1 wave
#define NTH 256
#define NBOX 16384
#define NCLSIN 91
#define NCLS 90
#define MAXSEL 100
#define TOPK 200
#define CAP 1024      // global candidate list stride per (b,c)
#define CANDL 512     // band capacity handled by prep/walk (C ~ 246 +- 16)
#define CBCAP 384     // staged boxes/areas
#define BINS 1024     // topk radix bins
#define GRP 4         // BINS / NTH
#define T0 0.985f     // band threshold; exact argmax fallback guards
#define BOXPB 256     // boxes per filter block
#define KSL 16        // per-class LDS slots per filter block
#define OVFC 64       // LDS overflow list capacity
#define CNTSTR 16     // cnt_g stride in ints (64B per counter)

// order-preserving fp32 <-> u32 (strictly monotone for all non-NaN)
__device__ __forceinline__ unsigned fmap(float f) {
    unsigned u = __float_as_uint(f);
    return (u & 0x80000000u) ? ~u : (u | 0x80000000u);
}
__device__ __forceinline__ float funmap(unsigned u) {
    unsigned b = (u & 0x80000000u) ? (u ^ 0x80000000u) : ~u;
    return __uint_as_float(b);
}
__device__ __forceinline__ unsigned long long shfl_xor_u64(unsigned long long v, int mask) {
    unsigned lo = (unsigned)(v & 0xFFFFFFFFull);
    unsigned hi = (unsigned)(v >> 32);
    lo = __shfl_xor(lo, mask, 64);
    hi = __shfl_xor(hi, mask, 64);
    return ((unsigned long long)hi << 32) | (unsigned long long)lo;
}

// exact reference IoU>0.5 test (same op order, real IEEE div, no FMA)
__device__ __forceinline__ bool sup_test(float4 s, float sa, float4 c, float ca) {
    float y1 = fmaxf(s.x, c.x);
    float x1 = fmaxf(s.y, c.y);
    float y2 = fminf(s.z, c.z);
    float x2 = fminf(s.w, c.w);
    float dy = fmaxf(__fsub_rn(y2, y1), 0.f);
    float dx = fmaxf(__fsub_rn(x2, x1), 0.f);
    float inter = __fmul_rn(dy, dx);
    float uni = __fsub_rn(__fadd_rn(sa, ca), inter);
    return (uni > 0.f) && (__fdiv_rn(inter, uni) > 0.5f);
}
__device__ __forceinline__ float box_area(float4 b) {
    return __fmul_rn(__fsub_rn(b.z, b.x), __fsub_rn(b.w, b.y));
}

// ---------------------------------------------------------------------------
// Kernel -1: zero the counters (runtime fillBuffer costs 54 us for 92 KB;
// this kernel does it in ~2 us).
// ---------------------------------------------------------------------------
__global__ __launch_bounds__(NTH) void zero_k(int4* __restrict__ p, int n4) {
    int i = blockIdx.x * NTH + threadIdx.x;
    if (i < n4) p[i] = make_int4(0, 0, 0, 0);
}

// ---------------------------------------------------------------------------
// filter_k helper: route one hit into per-class LDS staging. Exact.
// ---------------------------------------------------------------------------
__device__ __forceinline__ void emit_hit(unsigned long long pk, int b, int n0,
                                         int* cnt_s, unsigned long long* ent,
                                         unsigned* ovf_meta,
                                         unsigned long long* ovf_key,
                                         int* sh_ovf, int* cnt_g) {
    unsigned ee = (unsigned)pk;
    int row = (int)ee / NCLSIN;
    int c = (int)ee - row * NCLSIN;
    if (c == 0) return;  // background
    unsigned i = (unsigned)(n0 + row);
    unsigned long long key = (pk & 0xFFFFFFFF00000000ull) | (0xFFFFFFFFu - i);
    int r = atomicAdd(&cnt_s[c], 1);
    if (r < KSL) {
        ent[c * KSL + r] = key;
    } else {
        int o = atomicAdd(sh_ovf, 1);
        if (o < OVFC) {
            ovf_meta[o] = ((unsigned)c << 16) | (unsigned)r;
            ovf_key[o] = key;
        } else {
            // astronomically rare: force exact full fallback for this class
            atomicAdd(&cnt_g[(b * NCLS + c - 1) * CNTSTR], CAP + 1);
        }
    }
}

// ---------------------------------------------------------------------------
// Kernel 0: stream scores once (2x float4/lane). Hits buffered in 4 per-lane
// registers, drained at end; >=5th hit spills to immediate path.
// ---------------------------------------------------------------------------
__global__ __launch_bounds__(NTH) void filter_k(const float* __restrict__ in,
                                                unsigned long long* __restrict__ cand_g,
                                                int* __restrict__ cnt_g) {
    __shared__ int cnt_s[NCLSIN];
    __shared__ int base_s[NCLSIN];
    __shared__ unsigned long long ent[NCLSIN * KSL];
    __shared__ unsigned ovf_meta[OVFC];
    __shared__ unsigned long long ovf_key[OVFC];
    __shared__ int sh_ovf;

    const int tid = threadIdx.x;
    const int n0 = blockIdx.x * BOXPB;
    const int b = blockIdx.y;
    const int NF4 = BOXPB * NCLSIN / 4;

    for (int i = tid; i < NCLSIN; i += NTH) cnt_s[i] = 0;
    if (tid == 0) sh_ovf = 0;
    __syncthreads();

    unsigned long long q0 = 0, q1 = 0, q2 = 0, q3 = 0;
    int lc = 0;

    const float4* src = (const float4*)(in + ((size_t)b * NBOX + n0) * NCLSIN);
    for (int i = tid; i < NF4; i += 2 * NTH) {
        float4 v1 = src[i];
        int i2 = i + NTH;
        bool has2 = i2 < NF4;
        float4 v2 = make_float4(0.f, 0.f, 0.f, 0.f);
        if (has2) v2 = src[i2];
        float mx1 = fmaxf(fmaxf(v1.x, v1.y), fmaxf(v1.z, v1.w));
        float mx2 = fmaxf(fmaxf(v2.x, v2.y), fmaxf(v2.z, v2.w));
        if (fmaxf(mx1, mx2) > T0) {
#pragma unroll
            for (int h = 0; h < 2; ++h) {
                float4 v = h ? v2 : v1;
                float mx = h ? mx2 : mx1;
                int eb = (h ? i2 : i) * 4;
                if (mx > T0) {
                    const float sv[4] = {v.x, v.y, v.z, v.w};
#pragma unroll
                    for (int qq = 0; qq < 4; ++qq) {
                        float s = sv[qq];
                        if (s > T0) {
                            unsigned long long pk =
                                ((unsigned long long)fmap(s) << 32) |
                                (unsigned)(eb + qq);
                            if (lc == 0) q0 = pk;
                            else if (lc == 1) q1 = pk;
                            else if (lc == 2) q2 = pk;
                            else if (lc == 3) q3 = pk;
                            else emit_hit(pk, b, n0, cnt_s, ent, ovf_meta,
                                          ovf_key, &sh_ovf, cnt_g);
                            ++lc;
                        }
                    }
                }
            }
        }
    }
    if (lc > 0) emit_hit(q0, b, n0, cnt_s, ent, ovf_meta, ovf_key, &sh_ovf, cnt_g);
    if (lc > 1) emit_hit(q1, b, n0, cnt_s, ent, ovf_meta, ovf_key, &sh_ovf, cnt_g);
    if (lc > 2) emit_hit(q2, b, n0, cnt_s, ent, ovf_meta, ovf_key, &sh_ovf, cnt_g);
    if (lc > 3) emit_hit(q3, b, n0, cnt_s, ent, ovf_meta, ovf_key, &sh_ovf, cnt_g);
    __syncthreads();

    if (tid >= 1 && tid < NCLSIN) {
        int c = tid;
        int n = cnt_s[c];
        int base = 0;
        if (n > 0) {
            int bc = b * NCLS + c - 1;
            base = atomicAdd(&cnt_g[bc * CNTSTR], n);
            int lim = n < KSL ? n : KSL;
            for (int j = 0; j < lim; ++j) {
                int pos = base + j;
                if (pos < CAP) cand_g[(size_t)bc * CAP + pos] = ent[c * KSL + j];
            }
        }
        base_s[c] = base;
    }
    __syncthreads();

    int no = sh_ovf < OVFC ? sh_ovf : OVFC;
    for (int o = tid; o < no; o += NTH) {
        unsigned m = ovf_meta[o];
        int c = (int)(m >> 16);
        int r = (int)(m & 0xFFFFu);
        int bc = b * NCLS + c - 1;
        int pos = base_s[c] + r;
        if (pos < CAP) cand_g[(size_t)bc * CAP + pos] = ovf_key[o];
    }
}

// ---------------------------------------------------------------------------
// Kernel 1a: prep — sort each band list descending, in place. 256 threads.
// ---------------------------------------------------------------------------
__global__ __launch_bounds__(NTH) void prep_k(unsigned long long* __restrict__ cand_g,
                                              const int* __restrict__ cnt_g) {
    __shared__ unsigned long long s[CANDL];  // 4 KB
    const int tid = threadIdx.x;
    const int bc = blockIdx.y * NCLS + blockIdx.x;
    const int C = cnt_g[bc * CNTSTR];
    if (C <= 0 || C > CANDL) return;  // uniform; walk_k handles via fallback

    unsigned long long* cg = cand_g + (size_t)bc * CAP;
    for (int i = tid; i < C; i += NTH) s[i] = cg[i];
    int P = 1;
    while (P < C) P <<= 1;
    for (int i = C + tid; i < P; i += NTH) s[i] = 0ull;
    __syncthreads();
    for (int kk = 2; kk <= P; kk <<= 1) {
        for (int jj = kk >> 1; jj > 0; jj >>= 1) {
            for (int i = tid; i < P; i += NTH) {
                int ixj = i ^ jj;
                if (ixj > i) {
                    unsigned long long a = s[i], c = s[ixj];
                    bool sw = ((i & kk) == 0) ? (a < c) : (a > c);
                    if (sw) { s[i] = c; s[ixj] = a; }
                }
            }
            __syncthreads();
        }
    }
    for (int i = tid; i < C; i += NTH) cg[i] = s[i];
}

// ---------------------------------------------------------------------------
// Kernel 1b: walk — ONE WAVE per (batch, class). Stage sorted band into LDS
// (keys + boxes + areas), prefetched serial greedy walk, selections in
// 2 register slots/lane. Exact argmax fallback for all rare paths.
// ---------------------------------------------------------------------------
__global__ __launch_bounds__(WTH) void walk_k(
    const unsigned long long* __restrict__ cand_g,
    const int* __restrict__ cnt_g,
    const float* __restrict__ scores_raw,
    const float4* __restrict__ boxes,
    float* __restrict__ ws_sc, float* __restrict__ ws_bx, int use_band) {
    __shared__ unsigned long long kk[CANDL];  // 4 KB
    __shared__ float4 kbox[CBCAP];            // 6 KB
    __shared__ float karea[CBCAP];            // 1.5 KB

    const int tid = threadIdx.x;  // 0..63
    const int bc = blockIdx.x;
    const int b = bc / NCLS;
    const int c0 = bc - b * NCLS;
    const float* sraw = scores_raw + (size_t)b * NBOX * NCLSIN + (c0 + 1);
    const float4* bbase = boxes + (size_t)b * NBOX;

    float4 sel0 = make_float4(0.f, 0.f, 0.f, 0.f);
    float4 sel1 = make_float4(0.f, 0.f, 0.f, 0.f);
    float sa0 = 0.f, sa1 = 0.f, ss0 = 0.f, ss1 = 0.f;
    int nsel = 0;
    unsigned long long lastk = ~0ull;

    const int C = use_band ? cnt_g[bc * CNTSTR] : 0;
    if (use_band && C > 0 && C <= CANDL) {
        for (int i = tid; i < C; i += WTH)
            kk[i] = cand_g[(size_t)bc * CAP + i];
        __syncthreads();
        const int W = C < CBCAP ? C : CBCAP;
        for (int i = tid; i < W; i += WTH) {
            float4 bx = bbase[(int)(0xFFFFFFFFu - (unsigned)kk[i])];
            kbox[i] = bx;
            karea[i] = box_area(bx);
        }
        __syncthreads();

        // prefetched serial walk over [0, W)
        unsigned long long kcur = kk[0];
        float4 bcur = kbox[0];
        float acur = karea[0];
        for (int m = 0; m < W && nsel < MAXSEL; ++m) {
            int mn = (m + 1 < W) ? m + 1 : m;
            unsigned long long knxt = kk[mn];   // prefetch next (hides LDS lat)
            float4 bnxt = kbox[mn];
            float anxt = karea[mn];
            bool sup = false;
            if (tid < nsel) sup = sup_test(sel0, sa0, bcur, acur);
            if (tid + 64 < nsel) sup = sup || sup_test(sel1, sa1, bcur, acur);
            if (!__any(sup)) {
                if (tid == nsel) { sel0 = bcur; sa0 = acur; ss0 = funmap((unsigned)(kcur >> 32)); }
                if (tid == nsel - 64) { sel1 = bcur; sa1 = acur; ss1 = funmap((unsigned)(kcur >> 32)); }
                nsel++;
            }
            kcur = knxt; bcur = bnxt; acur = anxt;
        }
        // slow tail [W, C): global box fetch (uniform -> broadcast)
        for (int mm = W; mm < C && nsel < MAXSEL; ++mm) {
            unsigned long long k = kk[mm];
            float4 bx = bbase[(int)(0xFFFFFFFFu - (unsigned)k)];
            float ca = box_area(bx);
            bool sup = false;
            if (tid < nsel) sup = sup_test(sel0, sa0, bx, ca);
            if (tid + 64 < nsel) sup = sup || sup_test(sel1, sa1, bx, ca);
            if (!__any(sup)) {
                if (tid == nsel) { sel0 = bx; sa0 = ca; ss0 = funmap((unsigned)(k >> 32)); }
                if (tid == nsel - 64) { sel1 = bx; sa1 = ca; ss1 = funmap((unsigned)(k >> 32)); }
                nsel++;
            }
        }
        lastk = kk[C - 1];  // smallest band key (all non-band keys are below)
    }

    // ---- exact iterative-argmax fallback (reference semantics; guards
    // C==0 / C>CANDL / band-exhausted; never runs on this distribution) ----
    while (nsel < MAXSEL) {
        unsigned long long best = 0ull;
        for (int i = tid; i < NBOX; i += WTH) {
            float s = sraw[(size_t)i * NCLSIN];
            if (s > 0.3f) {
                unsigned long long key =
                    ((unsigned long long)fmap(s) << 32) | (0xFFFFFFFFu - (unsigned)i);
                if (key < lastk && key > best) best = key;
            }
        }
#pragma unroll
        for (int off = 32; off > 0; off >>= 1) {
            unsigned long long o = shfl_xor_u64(best, off);
            best = best > o ? best : o;
        }
        if (best == 0ull) break;  // no eligible box left
        lastk = best;
        float4 bx = bbase[(int)(0xFFFFFFFFu - (unsigned)best)];
        float ca = box_area(bx);
        bool sup = false;
        if (tid < nsel) sup = sup_test(sel0, sa0, bx, ca);
        if (tid + 64 < nsel) sup = sup || sup_test(sel1, sa1, bx, ca);
        if (!__any(sup)) {  // if suppressed, it was masked in reference: skip
            if (tid == nsel) { sel0 = bx; sa0 = ca; ss0 = funmap((unsigned)(best >> 32)); }
            if (tid == nsel - 64) { sel1 = bx; sa1 = ca; ss1 = funmap((unsigned)(best >> 32)); }
            nsel++;
        }
    }

    // ---- outputs: selections in greedy order, zero-padded ----
    {
        float* scp = ws_sc + (size_t)bc * MAXSEL;
        float4* bxp = (float4*)(ws_bx + (size_t)bc * MAXSEL * 4);
        bool v = tid < nsel;
        scp[tid] = v ? ss0 : 0.f;
        bxp[tid] = v ? sel0 : make_float4(0.f, 0.f, 0.f, 0.f);
        int j1 = tid + 64;
        if (j1 < MAXSEL) {
            bool v2 = j1 < nsel;
            scp[j1] = v2 ? ss1 : 0.f;
            bxp[j1] = v2 ? sel1 : make_float4(0.f, 0.f, 0.f, 0.f);
        }
    }
}

__device__ __forceinline__ void bin_select(unsigned* hist, unsigned* gbuf,
                                           int* sh_g, int* sh_b, unsigned* sh_pb,
                                           int tid, unsigned need) {
    unsigned gs = 0;
#pragma unroll
    for (int q = 0; q < GRP; ++q) gs += hist[tid * GRP + q];
    gbuf[tid] = gs;
    __syncthreads();
    for (int off = 1; off < NTH; off <<= 1) {
        unsigned add = (tid >= off) ? gbuf[tid - off] : 0u;
        __syncthreads();
        gbuf[tid] += add;
        __syncthreads();
    }
    if (tid == 0) *sh_g = NTH - 1;
    __syncthreads();
    if (gbuf[tid] >= need && (tid == 0 || gbuf[tid - 1] < need)) *sh_g = tid;
    __syncthreads();
    if (tid == 0) {
        int g = *sh_g;
        unsigned acc = (g > 0) ? gbuf[g - 1] : 0u;
        int bs = g * GRP + (GRP - 1);
        unsigned pb = acc;
#pragma unroll
        for (int q = 0; q < GRP; ++q) {
            acc += hist[g * GRP + q];
            if (acc >= need) { bs = g * GRP + q; pb = acc; break; }
            pb = acc;
        }
        *sh_b = bs; *sh_pb = pb;
    }
    __syncthreads();
}

__device__ __forceinline__ void sort_desc(unsigned long long* cand, int M, int tid) {
    int P = 1;
    while (P < M) P <<= 1;
    for (int i = M + tid; i < P; i += NTH) cand[i] = 0ull;
    __syncthreads();
    for (int kk = 2; kk <= P; kk <<= 1) {
        for (int jj = kk >> 1; jj > 0; jj >>= 1) {
            for (int i = tid; i < P; i += NTH) {
                int ixj = i ^ jj;
                if (ixj > i) {
                    unsigned long long a = cand[i], c = cand[ixj];
                    bool sw = ((i & kk) == 0) ? (a < c) : (a > c);
                    if (sw) { cand[i] = c; cand[ixj] = a; }
                }
            }
            __syncthreads();
        }
    }
}

// ---------------------------------------------------------------------------
// Kernel 2: one block per batch: stable top-200 of 9000 via radix-select+sort.
// ---------------------------------------------------------------------------
__global__ __launch_bounds__(NTH) void topk_k(const float* __restrict__ ws_sc,
                                              const float* __restrict__ ws_bx,
                                              float* __restrict__ out_sc,
                                              float* __restrict__ out_bx) {
    __shared__ unsigned hist[BINS];
    __shared__ unsigned gbuf[NTH];
    __shared__ unsigned long long cand[CAP];
    __shared__ unsigned sh_kmax, sh_pb;
    __shared__ int sh_E, sh_g, sh_b, sh_cnt;

    const int tid = threadIdx.x;
    const int b = blockIdx.x;
    const int NF = NCLS * MAXSEL;  // 9000
    const float* sp = ws_sc + (size_t)b * NF;

    unsigned km = 0, ce = 0;
    for (int f = tid; f < NF; f += NTH) {
        unsigned k = __float_as_uint(sp[f]);
        if (k) { ce++; km = km > k ? km : k; }
    }
#pragma unroll
    for (int off = 32; off > 0; off >>= 1) {
        unsigned o = (unsigned)__shfl_xor((int)km, off, 64);
        km = km > o ? km : o;
        ce += (unsigned)__shfl_xor((int)ce, off, 64);
    }
    if ((tid & 63) == 0) { gbuf[tid >> 6] = km; gbuf[8 + (tid >> 6)] = ce; }
    __syncthreads();
    if (tid == 0) {
        unsigned m2 = 0, c2 = 0;
        for (int w = 0; w < NTH / 64; ++w) {
            m2 = m2 > gbuf[w] ? m2 : gbuf[w];
            c2 += gbuf[8 + w];
        }
        sh_kmax = m2; sh_E = (int)c2;
    }
    __syncthreads();
    const int E = sh_E;
    const unsigned kmax = sh_kmax;

    unsigned thr = 1u;
    if (E > TOPK) {
        for (int shift = 8;; shift += 4) {
            for (int i = tid; i < BINS; i += NTH) hist[i] = 0u;
            __syncthreads();
            for (int f = tid; f < NF; f += NTH) {
                unsigned k = __float_as_uint(sp[f]);
                if (k) {
                    unsigned bin = (kmax - k) >> shift;
                    if (bin < BINS - 1) atomicAdd(&hist[bin], 1u);
                }
            }
            __syncthreads();
            bin_select(hist, gbuf, &sh_g, &sh_b, &sh_pb, tid, (unsigned)TOPK);
            if (sh_b < BINS - 1) {
                long long t = (long long)kmax - ((long long)(sh_b + 1) << shift) + 1;
                thr = (t < 1) ? 1u : (unsigned)t;
                break;
            }
        }
    }

    if (tid == 0) sh_cnt = 0;
    __syncthreads();
    for (int f = tid; f < NF; f += NTH) {
        unsigned k = __float_as_uint(sp[f]);
        if (k >= thr) {
            int pos = atomicAdd(&sh_cnt, 1);
            if (pos < CAP)
                cand[pos] = ((unsigned long long)k << 32) | (0xFFFFFFFFu - (unsigned)f);
        }
    }
    __syncthreads();
    int M = sh_cnt < CAP ? sh_cnt : CAP;

    if (M < TOPK) {
        int lim = M + TOPK;
        if (lim > NF) lim = NF;
        for (int f = tid; f < lim; f += NTH) {
            unsigned k = __float_as_uint(sp[f]);
            if (k == 0) {
                int pos = atomicAdd(&sh_cnt, 1);
                if (pos < CAP)
                    cand[pos] = (unsigned long long)(0xFFFFFFFFu - (unsigned)f);
            }
        }
        __syncthreads();
        M = sh_cnt < CAP ? sh_cnt : CAP;
    }

    sort_desc(cand, M, tid);

    for (int k = tid; k < TOPK; k += NTH) {
        float cls = 0.f, s = 0.f;
        float4 bx = make_float4(0.f, 0.f, 0.f, 0.f);
        if (k < M) {
            unsigned long long key = cand[k];
            unsigned f = 0xFFFFFFFFu - (unsigned)key;
            s = __uint_as_float((unsigned)(key >> 32));
            cls = (s > 0.f) ? (float)(f / MAXSEL + 1) : 0.f;
            bx = *(const float4*)(ws_bx + ((size_t)b * NF + f) * 4);
        }
        out_sc[((size_t)b * TOPK + k) * 2 + 0] = cls;
        out_sc[((size_t)b * TOPK + k) * 2 + 1] = s;
        ((float4*)out_bx)[(size_t)b * TOPK + k] = bx;
    }
}

// ---------------------------------------------------------------------------
extern "C" void kernel_launch(void* const* d_in, const int* in_sizes, int n_in,
                              void* d_out, int out_size, void* d_ws, size_t ws_size,
                              hipStream_t stream) {
    const float* scores = (const float*)d_in[0];
    const float4* boxes = (const float4*)d_in[1];
    float* out = (float*)d_out;

    const int B = in_sizes[1] / (NBOX * 4);
    const int NBC = B * NCLS;

    // ws layout: cnt [NBC * CNTSTR ints] | cand [NBC*CAP u64] | sc | bx
    size_t off_cand = ((size_t)NBC * CNTSTR * 4 + 15) & ~(size_t)15;
    size_t off_sc = off_cand + (size_t)NBC * CAP * 8;
    size_t off_bx = off_sc + (size_t)NBC * MAXSEL * 4;
    size_t need = off_bx + (size_t)NBC * MAXSEL * 16;

    char* ws = (char*)d_ws;
    bool use_band = ws_size >= need;

    int* cnt_g;
    unsigned long long* cand_g;
    float *ws_sc, *ws_bx;
    if (use_band) {
        cnt_g = (int*)ws;
        cand_g = (unsigned long long*)(ws + off_cand);
        ws_sc = (float*)(ws + off_sc);
        ws_bx = (float*)(ws + off_bx);
    } else {
        cnt_g = (int*)ws;                  // unused
        cand_g = (unsigned long long*)ws;  // unused
        ws_sc = (float*)ws;
        ws_bx = ws_sc + (size_t)NBC * MAXSEL;
    }

    if (use_band) {
        int n4 = NBC * CNTSTR / 4;
        zero_k<<<(n4 + NTH - 1) / NTH, NTH, 0, stream>>>((int4*)cnt_g, n4);
        filter_k<<<dim3(NBOX / BOXPB, B), NTH, 0, stream>>>(scores, cand_g, cnt_g);
        prep_k<<<dim3(NCLS, B), NTH, 0, stream>>>(cand_g, cnt_g);
    }
    walk_k<<<NBC, WTH, 0, stream>>>(cand_g, cnt_g, scores, boxes,
                                    ws_sc, ws_bx, use_band ? 1 : 0);
    topk_k<<<B, NTH, 0, stream>>>(ws_sc, ws_bx, out, out + (size_t)B * TOPK * 2);
}